// Round 3
// baseline (589.930 us; speedup 1.0000x reference)
//
#include <hip/hip_runtime.h>
#include <hip/hip_bf16.h>

// Problem constants (GCN autoencoder)
#define N_NODES 10000
#define N_FEAT  512
#define HIDDEN  32
#define CODE    16

typedef __attribute__((ext_vector_type(8))) short  short8;
typedef __attribute__((ext_vector_type(4))) float  floatx4;

__device__ __forceinline__ float bf2f(unsigned short h) {
    return __uint_as_float(((unsigned int)h) << 16);
}
__device__ __forceinline__ unsigned short f2bf(float f) {
    unsigned int u = __float_as_uint(f);
    u += 0x7fffu + ((u >> 16) & 1u);   // RNE
    return (unsigned short)(u >> 16);
}
__device__ __forceinline__ float load_f(const void* p, size_t i, int isf32) {
    return isf32 ? ((const float*)p)[i] : bf2f(((const unsigned short*)p)[i]);
}
__device__ __forceinline__ int get_idx(const int* p, int e, int is64) {
    return is64 ? p[2 * (size_t)e] : p[e];   // LE low half holds value (<10000)
}

// ---------------------------------------------------------------------------
// K0: dtype detector (insurance; expectation: all fp32, int32 — flags 1,1,1,1,0,0).
// Waves 0..3: float tensors {x,W1,W2,ew}: sample even ushort slots. fp32 ->
//   uniform low-mantissa -> max(u&0x7fff)>=0x5000 w.h.p.; bf16 (|v|<=~6) -> <0x4100.
// Waves 4..5: {src,dst}: sample odd int32 slots. int64 -> high halves all 0.
// ---------------------------------------------------------------------------
__global__ __launch_bounds__(384) void k_detect(const unsigned short* __restrict__ t0,
                                                const unsigned short* __restrict__ t1,
                                                const unsigned short* __restrict__ t2,
                                                const unsigned short* __restrict__ t3,
                                                const int* __restrict__ i0,
                                                const int* __restrict__ i1,
                                                int* __restrict__ flags) {
    const int w    = threadIdx.x >> 6;
    const int lane = threadIdx.x & 63;
    unsigned int m = 0;
    if (w < 4) {
        const unsigned short* p = (w == 0) ? t0 : (w == 1) ? t1 : (w == 2) ? t2 : t3;
        for (int i = lane; i < 128; i += 64) {
            unsigned int v = (unsigned int)p[2 * i] & 0x7fffu;
            m = m > v ? m : v;
        }
    } else {
        const int* p = (w == 4) ? i0 : i1;
        for (int i = lane; i < 128; i += 64) {
            m |= (unsigned int)p[2 * i + 1];
        }
    }
#pragma unroll
    for (int off = 32; off > 0; off >>= 1) {
        unsigned int o = (unsigned int)__shfl_down((int)m, off, 64);
        m = (w < 4) ? (m > o ? m : o) : (m | o);
    }
    if (lane == 0) flags[w] = (w < 4) ? (m >= 0x5000u ? 1 : 0) : (m == 0u ? 1 : 0);
}

// ---------------------------------------------------------------------------
// K1: XW1 = x @ W1  [10000x512] @ [512x32] -> fp32.  VALU dot product.
// Thread t -> (n=t>>5, c=t&31); 32 c-threads share the x row (L1 broadcast);
// W1 (64KB) is L2/L1-hot.
// ---------------------------------------------------------------------------
__global__ __launch_bounds__(256) void k_xw1(const void* __restrict__ x,
                                             const void* __restrict__ W1,
                                             float* __restrict__ XW1,
                                             const int* __restrict__ flags) {
    const int xf32  = flags[0];
    const int w1f32 = flags[1];
    int t = blockIdx.x * 256 + threadIdx.x;
    if (t >= N_NODES * HIDDEN) return;
    const int n = t >> 5;
    const int c = t & 31;
    float acc = 0.f;
#pragma unroll 8
    for (int k = 0; k < N_FEAT; ++k) {
        float a = load_f(x,  (size_t)n * N_FEAT + k, xf32);
        float b = load_f(W1, (size_t)k * HIDDEN + c, w1f32);
        acc += a * b;
    }
    XW1[t] = acc;
}

// ---------------------------------------------------------------------------
// K2: Hacc[dst] += ew * XW1[src]   (32 feats/edge, fp32 atomics into L2)
// ---------------------------------------------------------------------------
__global__ __launch_bounds__(256) void k_spmm32(const void* __restrict__ ew,
                                                const int* __restrict__ src,
                                                const int* __restrict__ dst,
                                                const float* __restrict__ Xin,
                                                float* __restrict__ Hacc, int E,
                                                const int* __restrict__ flags) {
    const int ewf32 = flags[3];
    const int s64   = flags[4];
    const int d64   = flags[5];
    int t = blockIdx.x * 256 + threadIdx.x;
    int e = t >> 5;
    int f = t & 31;
    if (e >= E) return;
    float w = load_f(ew, e, ewf32);
    int   s = get_idx(src, e, s64);
    int   d = get_idx(dst, e, d64);
    float v = Xin[(size_t)s * HIDDEN + f] * w;
    atomicAdd(&Hacc[(size_t)d * HIDDEN + f], v);
}

// ---------------------------------------------------------------------------
// K3: HW2 = relu(Hacc) @ W2   [10000x32] @ [32x16] -> fp32
// ---------------------------------------------------------------------------
__global__ __launch_bounds__(256) void k_hw2(const float* __restrict__ H,
                                             const void* __restrict__ W2,
                                             float* __restrict__ HW2,
                                             const int* __restrict__ flags) {
    const int w2f32 = flags[2];
    int t = blockIdx.x * 256 + threadIdx.x;
    if (t >= N_NODES * CODE) return;
    int n = t >> 4;
    int c = t & 15;
    float acc = 0.f;
#pragma unroll
    for (int k = 0; k < HIDDEN; ++k) {
        float h = H[n * HIDDEN + k];
        h = h > 0.f ? h : 0.f;
        acc += h * load_f(W2, k * CODE + c, w2f32);
    }
    HW2[t] = acc;
}

// ---------------------------------------------------------------------------
// K4: Zacc[dst] += ew * HW2[src]   (16 feats/edge)
// ---------------------------------------------------------------------------
__global__ __launch_bounds__(256) void k_spmm16(const void* __restrict__ ew,
                                                const int* __restrict__ src,
                                                const int* __restrict__ dst,
                                                const float* __restrict__ Hin,
                                                float* __restrict__ Zacc, int E,
                                                const int* __restrict__ flags) {
    const int ewf32 = flags[3];
    const int s64   = flags[4];
    const int d64   = flags[5];
    int t = blockIdx.x * 256 + threadIdx.x;
    int e = t >> 4;
    int f = t & 15;
    if (e >= E) return;
    float w = load_f(ew, e, ewf32);
    int   s = get_idx(src, e, s64);
    int   d = get_idx(dst, e, d64);
    float v = Hin[(size_t)s * CODE + f] * w;
    atomicAdd(&Zacc[(size_t)d * CODE + f], v);
}

// ---------------------------------------------------------------------------
// K5: z fp32 -> bf16 (RNE) for MFMA decoder (|z|<=~0.3: rel err 2^-9, harmless)
// ---------------------------------------------------------------------------
__global__ __launch_bounds__(256) void k_cvt(const float* __restrict__ Z,
                                             unsigned short* __restrict__ zb) {
    int t = blockIdx.x * 256 + threadIdx.x;
    if (t >= N_NODES * CODE) return;
    zb[t] = f2bf(Z[t]);
}

// ---------------------------------------------------------------------------
// K6: out = sigmoid(zb @ zb^T), FP32 out [10000 x 10000]  (400 MB, write-bound)
// Block = 4 waves; block tile 64x64; wave = 16 rows x 64 cols.
// K=16 padded to 32: quads 2,3 carry zero fragments.
//
// EPILOGUE (R0 change): exploit ZZ^T symmetry for vectorized stores.
//   acc[t][r] = out[r0+quad*4+r][c0+t*16+l16]  (HW-verified C/D mapping)
//             = out[c0+t*16+l16][r0+quad*4+r]  (symmetry)
// The 4 regs of one accumulator are 4 CONSECUTIVE COLUMNS of row
// (c0+t*16+l16) -> one aligned float4 nontemporal store per accumulator.
// Tile (by,bx) transpose-writes tile (bx,by)'s region; the full 157x157
// Cartesian grid keeps coverage complete and bijective. N%4==0 so a single
// (row<N && colbase<N) check guards the whole float4.
// 16 predicated global_store_dword -> 4 global_store_dwordx4 nt per thread.
// ---------------------------------------------------------------------------
__global__ __launch_bounds__(256) void k_dec(const unsigned short* __restrict__ zb,
                                             float* __restrict__ out) {
    const int wave = threadIdx.x >> 6;
    const int lane = threadIdx.x & 63;
    const int l16  = lane & 15;
    const int quad = lane >> 4;

    const int r0 = blockIdx.y * 64 + wave * 16;
    const int c0 = blockIdx.x * 64;

    const short8 zero8 = {0, 0, 0, 0, 0, 0, 0, 0};

    int ra = r0 + l16;
    if (ra > N_NODES - 1) ra = N_NODES - 1;
    short8 afr = zero8;
    if (quad < 2) afr = *(const short8*)(zb + (size_t)ra * CODE + quad * 8);

    floatx4 acc[4];
#pragma unroll
    for (int t = 0; t < 4; ++t) {
        int cb = c0 + t * 16 + l16;
        if (cb > N_NODES - 1) cb = N_NODES - 1;
        short8 bfr = zero8;
        if (quad < 2) bfr = *(const short8*)(zb + (size_t)cb * CODE + quad * 8);
        floatx4 z4 = {0.f, 0.f, 0.f, 0.f};
        acc[t] = __builtin_amdgcn_mfma_f32_16x16x32_bf16(afr, bfr, z4, 0, 0, 0);
    }

#pragma unroll
    for (int t = 0; t < 4; ++t) {
        const int row  = c0 + t * 16 + l16;   // transposed row (symmetry)
        const int colb = r0 + quad * 4;       // 4 consecutive transposed cols
        floatx4 v;
#pragma unroll
        for (int r = 0; r < 4; ++r) {
            float s = acc[t][r];
            float e = __builtin_amdgcn_exp2f(-1.442695041f * s);
            v[r] = __builtin_amdgcn_rcpf(1.f + e);
        }
        if (row < N_NODES && colb < N_NODES) {
            __builtin_nontemporal_store(v, (floatx4*)(out + (size_t)row * N_NODES + colb));
        }
    }
}

// ---------------------------------------------------------------------------
extern "C" void kernel_launch(void* const* d_in, const int* in_sizes, int n_in,
                              void* d_out, int out_size, void* d_ws, size_t ws_size,
                              hipStream_t stream) {
    const void* x  = d_in[0];
    const void* W1 = d_in[1];
    const void* W2 = d_in[2];
    const void* ew = d_in[3];
    const int* src = (const int*)d_in[4];
    const int* dst = (const int*)d_in[5];
    float* out = (float*)d_out;
    const int E = in_sizes[3];   // 330000 edges

    // Workspace (float offsets), lifetime-reused (2.56 MB total):
    //  XW1  [0,      320000)  live: k_xw1 .. k_spmm32
    //  Hacc [320000, 640000)  live: memset .. k_hw2     (zeroed up front)
    //  HW2  [0,      160000)  live: k_hw2 .. k_spmm16   (over dead XW1)
    //  Zacc [160000, 320000)  live: memset2 .. k_cvt    (over dead XW1)
    //  zb   ushort @ float ofs 320000                    (over dead Hacc)
    //  flags int[6] @ float ofs 640000
    float* ws   = (float*)d_ws;
    float* XW1  = ws;
    float* Hacc = ws + 320000;
    float* HW2  = ws;
    float* Zacc = ws + 160000;
    unsigned short* zb = (unsigned short*)(ws + 320000);
    int* flags = (int*)(ws + 640000);

    hipMemsetAsync(Hacc, 0, 320000 * sizeof(float), stream);

    k_detect<<<1, 384, 0, stream>>>((const unsigned short*)x,
                                    (const unsigned short*)W1,
                                    (const unsigned short*)W2,
                                    (const unsigned short*)ew,
                                    src, dst, flags);

    k_xw1<<<(N_NODES * HIDDEN + 255) / 256, 256, 0, stream>>>(x, W1, XW1, flags);
    k_spmm32<<<(E * 32 + 255) / 256, 256, 0, stream>>>(ew, src, dst, XW1, Hacc, E, flags);
    hipMemsetAsync(Zacc, 0, 160000 * sizeof(float), stream);   // XW1 upper half dead
    k_hw2<<<(N_NODES * CODE + 255) / 256, 256, 0, stream>>>(Hacc, W2, HW2, flags);
    k_spmm16<<<(E * 16 + 255) / 256, 256, 0, stream>>>(ew, src, dst, HW2, Zacc, E, flags);
    k_cvt<<<(N_NODES * CODE + 255) / 256, 256, 0, stream>>>(Zacc, zb);

    dim3 grid((N_NODES + 63) / 64, (N_NODES + 63) / 64);
    k_dec<<<grid, 256, 0, stream>>>(zb, out);
}

// Round 4
// 528.012 us; speedup vs baseline: 1.1173x; 1.1173x over previous
//
#include <hip/hip_runtime.h>
#include <hip/hip_bf16.h>

// Problem constants (GCN autoencoder)
#define N_NODES 10000
#define N_FEAT  512
#define HIDDEN  32
#define CODE    16

typedef __attribute__((ext_vector_type(8))) short  short8;
typedef __attribute__((ext_vector_type(4))) float  floatx4;

__device__ __forceinline__ float bf2f(unsigned short h) {
    return __uint_as_float(((unsigned int)h) << 16);
}
__device__ __forceinline__ unsigned short f2bf(float f) {
    unsigned int u = __float_as_uint(f);
    u += 0x7fffu + ((u >> 16) & 1u);   // RNE
    return (unsigned short)(u >> 16);
}
__device__ __forceinline__ float load_f(const void* p, size_t i, int isf32) {
    return isf32 ? ((const float*)p)[i] : bf2f(((const unsigned short*)p)[i]);
}
__device__ __forceinline__ int get_idx(const int* p, int e, int is64) {
    return is64 ? p[2 * (size_t)e] : p[e];   // LE low half holds value (<10000)
}

// ---------------------------------------------------------------------------
// K0: dtype detector (insurance; expectation: all fp32, int32 — flags 1,1,1,1,0,0).
// ---------------------------------------------------------------------------
__global__ __launch_bounds__(384) void k_detect(const unsigned short* __restrict__ t0,
                                                const unsigned short* __restrict__ t1,
                                                const unsigned short* __restrict__ t2,
                                                const unsigned short* __restrict__ t3,
                                                const int* __restrict__ i0,
                                                const int* __restrict__ i1,
                                                int* __restrict__ flags) {
    const int w    = threadIdx.x >> 6;
    const int lane = threadIdx.x & 63;
    unsigned int m = 0;
    if (w < 4) {
        const unsigned short* p = (w == 0) ? t0 : (w == 1) ? t1 : (w == 2) ? t2 : t3;
        for (int i = lane; i < 128; i += 64) {
            unsigned int v = (unsigned int)p[2 * i] & 0x7fffu;
            m = m > v ? m : v;
        }
    } else {
        const int* p = (w == 4) ? i0 : i1;
        for (int i = lane; i < 128; i += 64) {
            m |= (unsigned int)p[2 * i + 1];
        }
    }
#pragma unroll
    for (int off = 32; off > 0; off >>= 1) {
        unsigned int o = (unsigned int)__shfl_down((int)m, off, 64);
        m = (w < 4) ? (m > o ? m : o) : (m | o);
    }
    if (lane == 0) flags[w] = (w < 4) ? (m >= 0x5000u ? 1 : 0) : (m == 0u ? 1 : 0);
}

// ---------------------------------------------------------------------------
// K1: XW1 = x @ W1  [10000x512] @ [512x32] -> fp32.
// R3: specialized all-fp32 fast path (uniform flag check hoisted out of the
// k-loop): float4 x loads (16B, broadcast across the 32 c-lanes) + scalar W1
// loads (one 128B L1/L2-hot line per wave-iter). Kills the per-element
// dual-dtype load+cndmask machinery (~2x dynamic instructions).
// Generic path kept as fallback for non-fp32 inputs.
// ---------------------------------------------------------------------------
__global__ __launch_bounds__(256) void k_xw1(const void* __restrict__ x,
                                             const void* __restrict__ W1,
                                             float* __restrict__ XW1,
                                             const int* __restrict__ flags) {
    const int xf32  = flags[0];
    const int w1f32 = flags[1];
    int t = blockIdx.x * 256 + threadIdx.x;
    if (t >= N_NODES * HIDDEN) return;
    const int n = t >> 5;
    const int c = t & 31;

    if (xf32 && w1f32) {               // expected path, wave-uniform branch
        const float* xr = (const float*)x + (size_t)n * N_FEAT;
        const float* w1 = (const float*)W1;
        float acc = 0.f;
#pragma unroll 4
        for (int k = 0; k < N_FEAT; k += 4) {
            floatx4 xa = *(const floatx4*)(xr + k);
            acc += xa[0] * w1[(k + 0) * HIDDEN + c];
            acc += xa[1] * w1[(k + 1) * HIDDEN + c];
            acc += xa[2] * w1[(k + 2) * HIDDEN + c];
            acc += xa[3] * w1[(k + 3) * HIDDEN + c];
        }
        XW1[t] = acc;
        return;
    }

    float acc = 0.f;                   // generic fallback
#pragma unroll 8
    for (int k = 0; k < N_FEAT; ++k) {
        float a = load_f(x,  (size_t)n * N_FEAT + k, xf32);
        float b = load_f(W1, (size_t)k * HIDDEN + c, w1f32);
        acc += a * b;
    }
    XW1[t] = acc;
}

// ---------------------------------------------------------------------------
// K2: Hacc[dst] += ew * XW1[src]   (32 feats/edge, fp32 atomics into L2)
// ---------------------------------------------------------------------------
__global__ __launch_bounds__(256) void k_spmm32(const void* __restrict__ ew,
                                                const int* __restrict__ src,
                                                const int* __restrict__ dst,
                                                const float* __restrict__ Xin,
                                                float* __restrict__ Hacc, int E,
                                                const int* __restrict__ flags) {
    const int ewf32 = flags[3];
    const int s64   = flags[4];
    const int d64   = flags[5];
    int t = blockIdx.x * 256 + threadIdx.x;
    int e = t >> 5;
    int f = t & 31;
    if (e >= E) return;
    float w = load_f(ew, e, ewf32);
    int   s = get_idx(src, e, s64);
    int   d = get_idx(dst, e, d64);
    float v = Xin[(size_t)s * HIDDEN + f] * w;
    atomicAdd(&Hacc[(size_t)d * HIDDEN + f], v);
}

// ---------------------------------------------------------------------------
// K3: HW2 = relu(Hacc) @ W2   [10000x32] @ [32x16] -> fp32
// ---------------------------------------------------------------------------
__global__ __launch_bounds__(256) void k_hw2(const float* __restrict__ H,
                                             const void* __restrict__ W2,
                                             float* __restrict__ HW2,
                                             const int* __restrict__ flags) {
    const int w2f32 = flags[2];
    int t = blockIdx.x * 256 + threadIdx.x;
    if (t >= N_NODES * CODE) return;
    int n = t >> 4;
    int c = t & 15;
    float acc = 0.f;
#pragma unroll
    for (int k = 0; k < HIDDEN; ++k) {
        float h = H[n * HIDDEN + k];
        h = h > 0.f ? h : 0.f;
        acc += h * load_f(W2, k * CODE + c, w2f32);
    }
    HW2[t] = acc;
}

// ---------------------------------------------------------------------------
// K4: Zacc[dst] += ew * HW2[src]   (16 feats/edge)
// ---------------------------------------------------------------------------
__global__ __launch_bounds__(256) void k_spmm16(const void* __restrict__ ew,
                                                const int* __restrict__ src,
                                                const int* __restrict__ dst,
                                                const float* __restrict__ Hin,
                                                float* __restrict__ Zacc, int E,
                                                const int* __restrict__ flags) {
    const int ewf32 = flags[3];
    const int s64   = flags[4];
    const int d64   = flags[5];
    int t = blockIdx.x * 256 + threadIdx.x;
    int e = t >> 4;
    int f = t & 15;
    if (e >= E) return;
    float w = load_f(ew, e, ewf32);
    int   s = get_idx(src, e, s64);
    int   d = get_idx(dst, e, d64);
    float v = Hin[(size_t)s * CODE + f] * w;
    atomicAdd(&Zacc[(size_t)d * CODE + f], v);
}

// ---------------------------------------------------------------------------
// K5: z fp32 -> bf16 (RNE) for MFMA decoder (|z|<=~0.3: rel err 2^-9, harmless)
// ---------------------------------------------------------------------------
__global__ __launch_bounds__(256) void k_cvt(const float* __restrict__ Z,
                                             unsigned short* __restrict__ zb) {
    int t = blockIdx.x * 256 + threadIdx.x;
    if (t >= N_NODES * CODE) return;
    zb[t] = f2bf(Z[t]);
}

// ---------------------------------------------------------------------------
// K6: out = sigmoid(zb @ zb^T), FP32 out [10000 x 10000]  (400 MB, write-bound)
// Block = 4 waves; block tile 64x64; wave computes 16 rows. K=16 padded to 32.
//
// R3 epilogue: LDS-staged full-line drain.
//   Direct MFMA-layout stores emit 64B segments scattered across rows 40KB
//   apart -> partial 128B lines at HBM (R0's NT float4 kept the same 64B
//   segmentation; measured neutral). Now: stage the 64x64 fp32 tile in LDS
//   (row stride 68 floats: 16B-aligned, <=2-way bank aliasing = free), then
//   drain row-major: per pass each wave stores 4 rows x 256B CONTIGUOUS.
//   Every 128B line is fully covered by one instruction of one wave ->
//   nontemporal is safe (no partial lines) and avoids thrashing L2 with the
//   400MB stream. Sigmoid applied during drain.
// ---------------------------------------------------------------------------
#define TLD 68   // LDS row stride in floats (64 data + 4 pad)

__global__ __launch_bounds__(256) void k_dec(const unsigned short* __restrict__ zb,
                                             float* __restrict__ out) {
    __shared__ float tile[64 * TLD];   // 17.4 KB

    const int wave = threadIdx.x >> 6;
    const int lane = threadIdx.x & 63;
    const int l16  = lane & 15;
    const int quad = lane >> 4;

    const int rblk = blockIdx.y * 64;
    const int cblk = blockIdx.x * 64;
    const int r0   = rblk + wave * 16;

    const short8 zero8 = {0, 0, 0, 0, 0, 0, 0, 0};

    int ra = r0 + l16;
    if (ra > N_NODES - 1) ra = N_NODES - 1;
    short8 afr = zero8;
    if (quad < 2) afr = *(const short8*)(zb + (size_t)ra * CODE + quad * 8);

#pragma unroll
    for (int t = 0; t < 4; ++t) {
        int cb = cblk + t * 16 + l16;
        if (cb > N_NODES - 1) cb = N_NODES - 1;
        short8 bfr = zero8;
        if (quad < 2) bfr = *(const short8*)(zb + (size_t)cb * CODE + quad * 8);
        floatx4 z4 = {0.f, 0.f, 0.f, 0.f};
        floatx4 acc = __builtin_amdgcn_mfma_f32_16x16x32_bf16(afr, bfr, z4, 0, 0, 0);
        // C/D mapping: D[row=quad*4+r][col=l16] (HW-verified) ->
        // tile row = wave*16 + quad*4 + r, tile col = t*16 + l16
        const int lrow = wave * 16 + quad * 4;
        const int lcol = t * 16 + l16;
#pragma unroll
        for (int r = 0; r < 4; ++r) {
            tile[(lrow + r) * TLD + lcol] = acc[r];
        }
    }
    __syncthreads();

    // Drain: 4 passes x (16 rows x 64 cols). Per wave-store: 4 rows x 256B
    // contiguous (16 lanes x float4 per row).
    const int drow = threadIdx.x >> 4;          // 0..15
    const int dcol = (threadIdx.x & 15) * 4;    // 0,4,..,60
#pragma unroll
    for (int p = 0; p < 4; ++p) {
        const int lr = p * 16 + drow;
        floatx4 v;
#pragma unroll
        for (int j = 0; j < 4; ++j) {
            float s = tile[lr * TLD + dcol + j];
            float e = __builtin_amdgcn_exp2f(-1.442695041f * s);
            v[j] = __builtin_amdgcn_rcpf(1.f + e);
        }
        const int grow = rblk + lr;
        const int gcol = cblk + dcol;
        if (grow < N_NODES && gcol < N_NODES) {   // N%4==0: float4-exact guard
            __builtin_nontemporal_store(v, (floatx4*)(out + (size_t)grow * N_NODES + gcol));
        }
    }
}

// ---------------------------------------------------------------------------
extern "C" void kernel_launch(void* const* d_in, const int* in_sizes, int n_in,
                              void* d_out, int out_size, void* d_ws, size_t ws_size,
                              hipStream_t stream) {
    const void* x  = d_in[0];
    const void* W1 = d_in[1];
    const void* W2 = d_in[2];
    const void* ew = d_in[3];
    const int* src = (const int*)d_in[4];
    const int* dst = (const int*)d_in[5];
    float* out = (float*)d_out;
    const int E = in_sizes[3];   // 330000 edges

    // Workspace (float offsets), lifetime-reused (2.56 MB total):
    //  XW1  [0,      320000)  live: k_xw1 .. k_spmm32
    //  Hacc [320000, 640000)  live: memset .. k_hw2     (zeroed up front)
    //  HW2  [0,      160000)  live: k_hw2 .. k_spmm16   (over dead XW1)
    //  Zacc [160000, 320000)  live: memset2 .. k_cvt    (over dead XW1)
    //  zb   ushort @ float ofs 320000                    (over dead Hacc)
    //  flags int[6] @ float ofs 640000
    float* ws   = (float*)d_ws;
    float* XW1  = ws;
    float* Hacc = ws + 320000;
    float* HW2  = ws;
    float* Zacc = ws + 160000;
    unsigned short* zb = (unsigned short*)(ws + 320000);
    int* flags = (int*)(ws + 640000);

    hipMemsetAsync(Hacc, 0, 320000 * sizeof(float), stream);

    k_detect<<<1, 384, 0, stream>>>((const unsigned short*)x,
                                    (const unsigned short*)W1,
                                    (const unsigned short*)W2,
                                    (const unsigned short*)ew,
                                    src, dst, flags);

    k_xw1<<<(N_NODES * HIDDEN + 255) / 256, 256, 0, stream>>>(x, W1, XW1, flags);
    k_spmm32<<<(E * 32 + 255) / 256, 256, 0, stream>>>(ew, src, dst, XW1, Hacc, E, flags);
    hipMemsetAsync(Zacc, 0, 160000 * sizeof(float), stream);   // XW1 upper half dead
    k_hw2<<<(N_NODES * CODE + 255) / 256, 256, 0, stream>>>(Hacc, W2, HW2, flags);
    k_spmm16<<<(E * 16 + 255) / 256, 256, 0, stream>>>(ew, src, dst, HW2, Zacc, E, flags);
    k_cvt<<<(N_NODES * CODE + 255) / 256, 256, 0, stream>>>(Zacc, zb);

    dim3 grid((N_NODES + 63) / 64, (N_NODES + 63) / 64);
    k_dec<<<grid, 256, 0, stream>>>(zb, out);
}